// Round 1
// baseline (524.872 us; speedup 1.0000x reference)
//
#include <hip/hip_runtime.h>
#include <hip/hip_bf16.h>

#define NB    4096   // batch rows
#define NK    4      // modalities
#define ND    1024   // d_in
#define NH    1024   // hidden out
#define NCTX  256
#define NRH   64

typedef float f32x4 __attribute__((ext_vector_type(4)));
typedef float f32x8 __attribute__((ext_vector_type(8)));
typedef short s16x8 __attribute__((ext_vector_type(8)));
typedef __bf16 bf16x8 __attribute__((ext_vector_type(8)));

__device__ __forceinline__ unsigned short f2bf_rne(float f) {
    unsigned int u = __float_as_uint(f);
    u += 0x7fffu + ((u >> 16) & 1u);
    return (unsigned short)(u >> 16);
}
__device__ __forceinline__ float bf2f(unsigned short s) {
    return __uint_as_float(((unsigned int)s) << 16);
}

// ---------------------------------------------------------------------------
// Kernel 1: router MLP -> gates[B][K] = (mask>0.5)*mask*softmax(fusion_w)[k]
// 256 blocks x 256 threads; each wave handles 4 rows (shared W1/W2 loads).
// ---------------------------------------------------------------------------
__global__ __launch_bounds__(256) void router_k(
    const float* __restrict__ ctx, const float* __restrict__ gum,
    const float* __restrict__ W1, const float* __restrict__ b1,
    const float* __restrict__ gln, const float* __restrict__ bln,
    const float* __restrict__ W2, const float* __restrict__ b2,
    const float* __restrict__ W3, const float* __restrict__ b3,
    const float* __restrict__ prior, const float* __restrict__ fw,
    float* __restrict__ gates)
{
    __shared__ float sH[4][4][64];   // [wave][row][j]
    __shared__ float sH2[4][4][32];

    const int tid  = threadIdx.x;
    const int w    = tid >> 6;
    const int lane = tid & 63;
    const int rowbase = blockIdx.x * 16 + w * 4;
    const int rbu = __builtin_amdgcn_readfirstlane(rowbase);
    const float* c0 = ctx + (size_t)rbu * NCTX;   // wave-uniform -> scalar loads

    // ---- layer 1: h = ctx @ W1 + b1  (4 rows per wave, lane = hidden j) ----
    float a0 = 0.f, a1 = 0.f, a2 = 0.f, a3 = 0.f;
#pragma unroll 8
    for (int d = 0; d < NCTX; ++d) {
        float wv = W1[d * NRH + lane];
        a0 = fmaf(c0[d],          wv, a0);
        a1 = fmaf(c0[NCTX + d],   wv, a1);
        a2 = fmaf(c0[2*NCTX + d], wv, a2);
        a3 = fmaf(c0[3*NCTX + d], wv, a3);
    }
    const float bb = b1[lane];
    float hr[4] = {a0 + bb, a1 + bb, a2 + bb, a3 + bb};
    const float gl = gln[lane], be = bln[lane];

    // ---- LayerNorm + ReLU per row ----
#pragma unroll
    for (int r = 0; r < 4; ++r) {
        float h = hr[r];
        float s = h;
#pragma unroll
        for (int m = 32; m >= 1; m >>= 1) s += __shfl_xor(s, m);
        float mu = s * (1.f / 64.f);
        float dd = h - mu;
        float q = dd * dd;
#pragma unroll
        for (int m = 32; m >= 1; m >>= 1) q += __shfl_xor(q, m);
        float var = q * (1.f / 64.f);
        h = dd * rsqrtf(var + 1e-5f) * gl + be;
        sH[w][r][lane] = fmaxf(h, 0.f);
    }

    // ---- layer 2: relu(h @ W2 + b2), 2 rows per pass (lane>>5 picks row) ----
#pragma unroll
    for (int p = 0; p < 2; ++p) {
        const int r = p * 2 + (lane >> 5);
        const int j = lane & 31;
        float acc = b2[j];
#pragma unroll 8
        for (int l = 0; l < 64; ++l)
            acc = fmaf(sH[w][r][l], W2[l * 32 + j], acc);
        sH2[w][r][j] = fmaxf(acc, 0.f);
    }

    // ---- layer 3 + gating: lanes 0..15 = (row r3, modality j3) ----
    const int r3 = lane >> 2, j3 = lane & 3;
    float lg = 0.f;
    if (lane < 16) {
        lg = b3[j3] + prior[j3];
#pragma unroll 8
        for (int l = 0; l < 32; ++l)
            lg = fmaf(sH2[w][r3][l], W3[l * 4 + j3], lg);
    }
    float pj = 1.f / (1.f + expf(-lg));
    const int base = lane & 60;
    float P0 = __shfl(pj, base), P1 = __shfl(pj, base | 1);
    float P2 = __shfl(pj, base | 2), P3 = __shfl(pj, base | 3);

    if (lane < 16) {
        // softmax(fusion_w)[j3]
        float f0 = fw[0], f1 = fw[1], f2 = fw[2], f3 = fw[3];
        float fm = fmaxf(fmaxf(f0, f1), fmaxf(f2, f3));
        float e0 = expf(f0 - fm), e1 = expf(f1 - fm), e2 = expf(f2 - fm), e3 = expf(f3 - fm);
        float es = e0 + e1 + e2 + e3;
        float wsm = (j3 == 0 ? e0 : j3 == 1 ? e1 : j3 == 2 ? e2 : e3) / es;

        // top-2 membership (ties -> lower index, matching lax.top_k)
        int cnt = 0;
        cnt += (P0 > pj) || ((P0 == pj) && (0 < j3));
        cnt += (P1 > pj) || ((P1 == pj) && (1 < j3));
        cnt += (P2 > pj) || ((P2 == pj) && (2 < j3));
        cnt += (P3 > pj) || ((P3 == pj) && (3 < j3));

        const int row = rowbase + r3;
        float soft = 1.f / (1.f + expf(-(lg + gum[row * 4 + j3])));
        float mask = (cnt < 2) ? 1.0f : soft;       // max(soft, min_mask)
        float gate = (mask > 0.5f) ? mask * wsm : 0.0f;
        gates[row * 4 + j3] = gate;
    }
}

// ---------------------------------------------------------------------------
// Kernel 2: W_enc [K][D][H] fp32  ->  Wt_hi/Wt_lo bf16 [K][H][D] (transposed,
// RNE hi + residual lo).  4096 blocks (k,dt,ht tiles of 32x32) x 256 thr.
// ---------------------------------------------------------------------------
__global__ __launch_bounds__(256) void wprep_k(
    const float* __restrict__ W, unsigned short* __restrict__ whi,
    unsigned short* __restrict__ wlo)
{
    __shared__ float sT[32][33];
    const int bid = blockIdx.x;
    const int k  = bid >> 10;
    const int dt = (bid >> 5) & 31;
    const int ht = bid & 31;
    const int t = threadIdx.x;
    {
        const int r  = t >> 3;
        const int c4 = (t & 7) << 2;
        const float* src = W + ((size_t)k << 20) + (size_t)(dt * 32 + r) * 1024 + (ht * 32 + c4);
        float4 v = *(const float4*)src;
        sT[c4 + 0][r] = v.x; sT[c4 + 1][r] = v.y;
        sT[c4 + 2][r] = v.z; sT[c4 + 3][r] = v.w;
    }
    __syncthreads();
    {
        const int h  = t >> 3;
        const int d4 = (t & 7) << 2;
        float u0 = sT[h][d4], u1 = sT[h][d4 + 1], u2 = sT[h][d4 + 2], u3 = sT[h][d4 + 3];
        ushort4 uh, ul;
        uh.x = f2bf_rne(u0); ul.x = f2bf_rne(u0 - bf2f(uh.x));
        uh.y = f2bf_rne(u1); ul.y = f2bf_rne(u1 - bf2f(uh.y));
        uh.z = f2bf_rne(u2); ul.z = f2bf_rne(u2 - bf2f(uh.z));
        uh.w = f2bf_rne(u3); ul.w = f2bf_rne(u3 - bf2f(uh.w));
        size_t o = ((size_t)k << 20) + (size_t)(ht * 32 + h) * 1024 + (dt * 32 + d4);
        *(ushort4*)(whi + o) = uh;
        *(ushort4*)(wlo + o) = ul;
    }
}

// ---------------------------------------------------------------------------
// Kernel 3: gated split-bf16 MFMA GEMM, fused bias + fusion weights.
// fused[b,h] = sum_k g[b,k] * (x[k,b,:] @ W_enc[k]) + sum_k g[b,k]*b_enc[k,h]
// M=4096 N=1024 K=4096.  No LDS, no barriers: per-fragment direct global
// loads (both operands k-contiguous 16B/lane).  256 blocks x 256 thr;
// 4 waves (2x2) x 64x64 tile each; 3-term hi/lo split per K-step of 32.
// ---------------------------------------------------------------------------
__global__ __launch_bounds__(256, 1) void gemm_k(
    const float* __restrict__ x, const unsigned short* __restrict__ whi,
    const unsigned short* __restrict__ wlo, const float* __restrict__ gates,
    const float* __restrict__ benc, float* __restrict__ out)
{
    const int bid = blockIdx.x;
    const int xcd = bid & 7;          // XCD-grouped bm so each XCD owns a
    const int idx = bid >> 3;         // contiguous row-strip (L2 locality)
    const int bm = xcd * 4 + (idx >> 3);
    const int bn = idx & 7;

    const int tid  = threadIdx.x;
    const int w    = tid >> 6, lane = tid & 63;
    const int wr   = w >> 1,  wc   = w & 1;
    const int l15  = lane & 15, ls = lane >> 4;
    const int rowb = bm * 128 + wr * 64;
    const int colb = bn * 128 + wc * 64;

    f32x4 acc[4][4];
#pragma unroll
    for (int a = 0; a < 4; ++a)
#pragma unroll
        for (int b = 0; b < 4; ++b)
            acc[a][b] = (f32x4){0.f, 0.f, 0.f, 0.f};

    const float* xa[4];
    const unsigned short* bha[4];
    const unsigned short* bla[4];
#pragma unroll
    for (int mi = 0; mi < 4; ++mi)
        xa[mi] = x + (size_t)(rowb + mi * 16 + l15) * ND + ls * 8;
#pragma unroll
    for (int ni = 0; ni < 4; ++ni) {
        size_t o = (size_t)(colb + ni * 16 + l15) * ND + ls * 8;
        bha[ni] = whi + o;
        bla[ni] = wlo + o;
    }

    for (int ks = 0; ks < NK; ++ks) {
        float ga[4];
#pragma unroll
        for (int mi = 0; mi < 4; ++mi)
            ga[mi] = gates[(rowb + mi * 16 + l15) * 4 + ks];
        const size_t xo = (size_t)ks * ((size_t)NB * ND);
        const size_t wo = (size_t)ks * ((size_t)NH * ND);

#pragma unroll 2
        for (int tt = 0; tt < 32; ++tt) {
            const int d0 = tt * 32;
            s16x8 ah[4], al[4], bh[4], blo[4];
#pragma unroll
            for (int ni = 0; ni < 4; ++ni) {
                bh[ni]  = *(const s16x8*)(bha[ni] + wo + d0);
                blo[ni] = *(const s16x8*)(bla[ni] + wo + d0);
            }
#pragma unroll
            for (int mi = 0; mi < 4; ++mi) {
                f32x8 v = *(const f32x8*)(xa[mi] + xo + d0);
                v *= ga[mi];                                   // fold gate into A
                bf16x8 hb = __builtin_convertvector(v, bf16x8);        // RNE hi
                f32x8  hf = __builtin_convertvector(hb, f32x8);
                bf16x8 lb = __builtin_convertvector(v - hf, bf16x8);   // residual lo
                ah[mi] = __builtin_bit_cast(s16x8, hb);
                al[mi] = __builtin_bit_cast(s16x8, lb);
            }
            // pass 1: Ah*Bh
#pragma unroll
            for (int mi = 0; mi < 4; ++mi)
#pragma unroll
                for (int ni = 0; ni < 4; ++ni)
                    acc[mi][ni] = __builtin_amdgcn_mfma_f32_16x16x32_bf16(
                        ah[mi], bh[ni], acc[mi][ni], 0, 0, 0);
            // pass 2: Ah*Bl
#pragma unroll
            for (int mi = 0; mi < 4; ++mi)
#pragma unroll
                for (int ni = 0; ni < 4; ++ni)
                    acc[mi][ni] = __builtin_amdgcn_mfma_f32_16x16x32_bf16(
                        ah[mi], blo[ni], acc[mi][ni], 0, 0, 0);
            // pass 3: Al*Bh
#pragma unroll
            for (int mi = 0; mi < 4; ++mi)
#pragma unroll
                for (int ni = 0; ni < 4; ++ni)
                    acc[mi][ni] = __builtin_amdgcn_mfma_f32_16x16x32_bf16(
                        al[mi], bh[ni], acc[mi][ni], 0, 0, 0);
        }
    }

    // ---- epilogue: + sum_k g[b,k]*b_enc[k,h]; C/D frag: row=(l>>4)*4+j, col=l&15
    float bcol[4][4];
#pragma unroll
    for (int ni = 0; ni < 4; ++ni) {
        const int col = colb + ni * 16 + l15;
#pragma unroll
        for (int kk = 0; kk < 4; ++kk)
            bcol[ni][kk] = benc[kk * NH + col];
    }
#pragma unroll
    for (int mi = 0; mi < 4; ++mi) {
#pragma unroll
        for (int j = 0; j < 4; ++j) {
            const int row = rowb + mi * 16 + ls * 4 + j;
            const float4 g = *(const float4*)(gates + row * 4);
#pragma unroll
            for (int ni = 0; ni < 4; ++ni) {
                const int col = colb + ni * 16 + l15;
                float bias = g.x * bcol[ni][0] + g.y * bcol[ni][1] +
                             g.z * bcol[ni][2] + g.w * bcol[ni][3];
                out[(size_t)row * NH + col] = acc[mi][ni][j] + bias;
            }
        }
    }
}

// ---------------------------------------------------------------------------
extern "C" void kernel_launch(void* const* d_in, const int* in_sizes, int n_in,
                              void* d_out, int out_size, void* d_ws, size_t ws_size,
                              hipStream_t stream)
{
    const float* ctx   = (const float*)d_in[0];
    const float* x     = (const float*)d_in[1];
    const float* gum   = (const float*)d_in[2];
    const float* W1    = (const float*)d_in[3];
    const float* b1    = (const float*)d_in[4];
    const float* gln   = (const float*)d_in[5];
    const float* bln   = (const float*)d_in[6];
    const float* W2    = (const float*)d_in[7];
    const float* b2    = (const float*)d_in[8];
    const float* W3    = (const float*)d_in[9];
    const float* b3    = (const float*)d_in[10];
    const float* prior = (const float*)d_in[11];
    const float* Wenc  = (const float*)d_in[12];
    const float* benc  = (const float*)d_in[13];
    const float* fw    = (const float*)d_in[14];
    float* out = (float*)d_out;

    // ws layout: gates 64KB | Wt_hi 8MB | Wt_lo 8MB  (total ~16.1MB)
    char* ws = (char*)d_ws;
    float* gates            = (float*)ws;
    unsigned short* whi     = (unsigned short*)(ws + (64 << 10));
    unsigned short* wlo     = (unsigned short*)(ws + (64 << 10) + (8 << 20));

    hipLaunchKernelGGL(router_k, dim3(256), dim3(256), 0, stream,
                       ctx, gum, W1, b1, gln, bln, W2, b2, W3, b3, prior, fw, gates);
    hipLaunchKernelGGL(wprep_k, dim3(4096), dim3(256), 0, stream, Wenc, whi, wlo);
    hipLaunchKernelGGL(gemm_k, dim3(256), dim3(256), 0, stream,
                       x, whi, wlo, gates, benc, out);
}

// Round 2
// 264.880 us; speedup vs baseline: 1.9816x; 1.9816x over previous
//
#include <hip/hip_runtime.h>
#include <hip/hip_bf16.h>

#define NB    4096   // batch rows
#define NK    4      // modalities
#define ND    1024   // d_in
#define NH    1024   // hidden out
#define NCTX  256
#define NRH   64

typedef float f32x4 __attribute__((ext_vector_type(4)));
typedef float f32x8 __attribute__((ext_vector_type(8)));
typedef short s16x8 __attribute__((ext_vector_type(8)));
typedef __bf16 bf16x8 __attribute__((ext_vector_type(8)));

__device__ __forceinline__ unsigned short f2bf_rne(float f) {
    unsigned int u = __float_as_uint(f);
    u += 0x7fffu + ((u >> 16) & 1u);
    return (unsigned short)(u >> 16);
}
__device__ __forceinline__ float bf2f(unsigned short s) {
    return __uint_as_float(((unsigned int)s) << 16);
}
__device__ __forceinline__ void gl_lds16(const void* g, void* l) {
    __builtin_amdgcn_global_load_lds(
        (const __attribute__((address_space(1))) unsigned int*)g,
        (__attribute__((address_space(3))) unsigned int*)l, 16, 0, 0);
}

// ---------------------------------------------------------------------------
// Kernel 1: router MLP -> gates[B][K] = (mask>0.5)*mask*softmax(fusion_w)[k]
// ---------------------------------------------------------------------------
__global__ __launch_bounds__(256) void router_k(
    const float* __restrict__ ctx, const float* __restrict__ gum,
    const float* __restrict__ W1, const float* __restrict__ b1,
    const float* __restrict__ gln, const float* __restrict__ bln,
    const float* __restrict__ W2, const float* __restrict__ b2,
    const float* __restrict__ W3, const float* __restrict__ b3,
    const float* __restrict__ prior, const float* __restrict__ fw,
    float* __restrict__ gates)
{
    __shared__ float sH[4][4][64];
    __shared__ float sH2[4][4][32];

    const int tid  = threadIdx.x;
    const int w    = tid >> 6;
    const int lane = tid & 63;
    const int rowbase = blockIdx.x * 16 + w * 4;
    const int rbu = __builtin_amdgcn_readfirstlane(rowbase);
    const float* c0 = ctx + (size_t)rbu * NCTX;

    float a0 = 0.f, a1 = 0.f, a2 = 0.f, a3 = 0.f;
#pragma unroll 8
    for (int d = 0; d < NCTX; ++d) {
        float wv = W1[d * NRH + lane];
        a0 = fmaf(c0[d],          wv, a0);
        a1 = fmaf(c0[NCTX + d],   wv, a1);
        a2 = fmaf(c0[2*NCTX + d], wv, a2);
        a3 = fmaf(c0[3*NCTX + d], wv, a3);
    }
    const float bb = b1[lane];
    float hr[4] = {a0 + bb, a1 + bb, a2 + bb, a3 + bb};
    const float gl = gln[lane], be = bln[lane];

#pragma unroll
    for (int r = 0; r < 4; ++r) {
        float h = hr[r];
        float s = h;
#pragma unroll
        for (int m = 32; m >= 1; m >>= 1) s += __shfl_xor(s, m);
        float mu = s * (1.f / 64.f);
        float dd = h - mu;
        float q = dd * dd;
#pragma unroll
        for (int m = 32; m >= 1; m >>= 1) q += __shfl_xor(q, m);
        float var = q * (1.f / 64.f);
        h = dd * rsqrtf(var + 1e-5f) * gl + be;
        sH[w][r][lane] = fmaxf(h, 0.f);
    }

#pragma unroll
    for (int p = 0; p < 2; ++p) {
        const int r = p * 2 + (lane >> 5);
        const int j = lane & 31;
        float acc = b2[j];
#pragma unroll 8
        for (int l = 0; l < 64; ++l)
            acc = fmaf(sH[w][r][l], W2[l * 32 + j], acc);
        sH2[w][r][j] = fmaxf(acc, 0.f);
    }

    const int r3 = lane >> 2, j3 = lane & 3;
    float lg = 0.f;
    if (lane < 16) {
        lg = b3[j3] + prior[j3];
#pragma unroll 8
        for (int l = 0; l < 32; ++l)
            lg = fmaf(sH2[w][r3][l], W3[l * 4 + j3], lg);
    }
    float pj = 1.f / (1.f + expf(-lg));
    const int base = lane & 60;
    float P0 = __shfl(pj, base), P1 = __shfl(pj, base | 1);
    float P2 = __shfl(pj, base | 2), P3 = __shfl(pj, base | 3);

    if (lane < 16) {
        float f0 = fw[0], f1 = fw[1], f2 = fw[2], f3 = fw[3];
        float fm = fmaxf(fmaxf(f0, f1), fmaxf(f2, f3));
        float e0 = expf(f0 - fm), e1 = expf(f1 - fm), e2 = expf(f2 - fm), e3 = expf(f3 - fm);
        float es = e0 + e1 + e2 + e3;
        float wsm = (j3 == 0 ? e0 : j3 == 1 ? e1 : j3 == 2 ? e2 : e3) / es;

        int cnt = 0;
        cnt += (P0 > pj) || ((P0 == pj) && (0 < j3));
        cnt += (P1 > pj) || ((P1 == pj) && (1 < j3));
        cnt += (P2 > pj) || ((P2 == pj) && (2 < j3));
        cnt += (P3 > pj) || ((P3 == pj) && (3 < j3));

        const int row = rowbase + r3;
        float soft = 1.f / (1.f + expf(-(lg + gum[row * 4 + j3])));
        float mask = (cnt < 2) ? 1.0f : soft;
        float gate = (mask > 0.5f) ? mask * wsm : 0.0f;
        gates[row * 4 + j3] = gate;
    }
}

// ---------------------------------------------------------------------------
// Kernel 2: W_enc [K][D][H] fp32 -> Bh/Bl bf16 [K][H][D] (transpose + split)
// ---------------------------------------------------------------------------
__global__ __launch_bounds__(256) void wprep_k(
    const float* __restrict__ W, unsigned short* __restrict__ whi,
    unsigned short* __restrict__ wlo)
{
    __shared__ float sT[32][33];
    const int bid = blockIdx.x;
    const int k  = bid >> 10;
    const int dt = (bid >> 5) & 31;
    const int ht = bid & 31;
    const int t = threadIdx.x;
    {
        const int r  = t >> 3;
        const int c4 = (t & 7) << 2;
        const float* src = W + ((size_t)k << 20) + (size_t)(dt * 32 + r) * 1024 + (ht * 32 + c4);
        float4 v = *(const float4*)src;
        sT[c4 + 0][r] = v.x; sT[c4 + 1][r] = v.y;
        sT[c4 + 2][r] = v.z; sT[c4 + 3][r] = v.w;
    }
    __syncthreads();
    {
        const int h  = t >> 3;
        const int d4 = (t & 7) << 2;
        float u0 = sT[h][d4], u1 = sT[h][d4 + 1], u2 = sT[h][d4 + 2], u3 = sT[h][d4 + 3];
        ushort4 uh, ul;
        uh.x = f2bf_rne(u0); ul.x = f2bf_rne(u0 - bf2f(uh.x));
        uh.y = f2bf_rne(u1); ul.y = f2bf_rne(u1 - bf2f(uh.y));
        uh.z = f2bf_rne(u2); ul.z = f2bf_rne(u2 - bf2f(uh.z));
        uh.w = f2bf_rne(u3); ul.w = f2bf_rne(u3 - bf2f(uh.w));
        size_t o = ((size_t)k << 20) + (size_t)(ht * 32 + h) * 1024 + (dt * 32 + d4);
        *(ushort4*)(whi + o) = uh;
        *(ushort4*)(wlo + o) = ul;
    }
}

// ---------------------------------------------------------------------------
// Kernel 3: A-prep: Ah/Al[b][ks*1024+d] = split(x[ks,b,d] * gates[b,ks])
// ---------------------------------------------------------------------------
__global__ __launch_bounds__(256) void aprep_k(
    const float* __restrict__ x, const float* __restrict__ gates,
    unsigned short* __restrict__ Ah, unsigned short* __restrict__ Al)
{
    const int bid = blockIdx.x;
    const int k  = bid >> 11;          // 0..3
    const int bp = bid & 2047;         // b pair
    const int t = threadIdx.x;
    const int boff = t >> 7;
    const int d8 = (t & 127) << 3;
    const int b = bp * 2 + boff;
    const float g = gates[b * 4 + k];  // wave-uniform

    f32x8 v = *(const f32x8*)(x + ((size_t)k << 22) + (size_t)b * ND + d8);
    v *= g;
    bf16x8 hb = __builtin_convertvector(v, bf16x8);
    f32x8  hf = __builtin_convertvector(hb, f32x8);
    bf16x8 lb = __builtin_convertvector(v - hf, bf16x8);
    const size_t o = (size_t)b * 4096 + (k << 10) + d8;
    *(s16x8*)(Ah + o) = __builtin_bit_cast(s16x8, hb);
    *(s16x8*)(Al + o) = __builtin_bit_cast(s16x8, lb);
}

// ---------------------------------------------------------------------------
// Kernel 4: bf16 hi/lo MFMA GEMM, LDS-staged (m97 structure).
// M=4096 N=1024 K=4096.  BM=128 BN=64 BK=64; 4 waves 2x2, wave tile 64x32;
// grid 512 (2 blk/CU).  LDS 48KB, T2 XOR-swizzle via pre-swizzled global src.
// ---------------------------------------------------------------------------
__global__ __launch_bounds__(256, 3) void gemm_k(
    const unsigned short* __restrict__ Ahg, const unsigned short* __restrict__ Alg,
    const unsigned short* __restrict__ Bhg, const unsigned short* __restrict__ Blg,
    const float* __restrict__ gates, const float* __restrict__ benc,
    float* __restrict__ out)
{
    __shared__ unsigned short sAh[128 * 64];
    __shared__ unsigned short sAl[128 * 64];
    __shared__ unsigned short sBh[64 * 64];
    __shared__ unsigned short sBl[64 * 64];

    const int bid = blockIdx.x;
    const int wg  = (bid & 7) * 64 + (bid >> 3);   // XCD-grouped, bijective
    const int bm  = wg >> 4;               // 0..31
    const int bn  = wg & 15;               // 0..15

    const int tid = threadIdx.x;
    const int wv  = tid >> 6, ln = tid & 63;
    const int wr  = wv >> 1,  wc = wv & 1;
    const int l15 = ln & 15,  ls = ln >> 4;
    const int rowb = bm * 128;
    const int colb = bn * 64;

    // staging: LDS byte L = chunk*1024 + l*16 holds (row = L>>7,
    // col_bytes = (L&127) ^ ((row&7)<<4)); row = chunk*8 + (l>>3)
    const int srow = ln >> 3;
    const int slot = (ln & 7) ^ srow;
    size_t aoff[4];
#pragma unroll
    for (int i = 0; i < 4; ++i) {
        const int row = (wv * 4 + i) * 8 + srow;
        aoff[i] = (size_t)(rowb + row) * 4096 + slot * 8;
    }
    size_t boff[2];
#pragma unroll
    for (int i = 0; i < 2; ++i) {
        const int row = (wv * 2 + i) * 8 + srow;
        boff[i] = (size_t)(colb + row) * 1024 + slot * 8;
    }

    const int arow0 = (wr * 64 + l15) * 128;
    const int brow0 = (wc * 32 + l15) * 128;
    const int xr = (l15 & 7) << 4;
    int colswz[2];
#pragma unroll
    for (int kk = 0; kk < 2; ++kk)
        colswz[kk] = ((kk << 6) + (ls << 4)) ^ xr;

    f32x4 acc[4][2];
#pragma unroll
    for (int a = 0; a < 4; ++a)
#pragma unroll
        for (int b = 0; b < 2; ++b)
            acc[a][b] = (f32x4){0.f, 0.f, 0.f, 0.f};

#pragma unroll 1
    for (int kt = 0; kt < 64; ++kt) {
        const int kbase = kt * 64;
        const size_t wkoff = ((size_t)(kt >> 4) << 20) + (size_t)(kt & 15) * 64;

#pragma unroll
        for (int i = 0; i < 4; ++i) {
            const int chunk = wv * 4 + i;
            gl_lds16(Ahg + aoff[i] + kbase, &sAh[chunk * 512]);
            gl_lds16(Alg + aoff[i] + kbase, &sAl[chunk * 512]);
        }
#pragma unroll
        for (int i = 0; i < 2; ++i) {
            const int chunk = wv * 2 + i;
            gl_lds16(Bhg + boff[i] + wkoff, &sBh[chunk * 512]);
            gl_lds16(Blg + boff[i] + wkoff, &sBl[chunk * 512]);
        }
        __syncthreads();   // vmcnt(0)+lgkmcnt(0) drain + barrier

#pragma unroll
        for (int kk = 0; kk < 2; ++kk) {
            s16x8 ah[4], al[4], bh[2], bl[2];
#pragma unroll
            for (int mi = 0; mi < 4; ++mi) {
                const int ab = arow0 + mi * 2048 + colswz[kk];
                ah[mi] = *(const s16x8*)((const char*)sAh + ab);
                al[mi] = *(const s16x8*)((const char*)sAl + ab);
            }
#pragma unroll
            for (int ni = 0; ni < 2; ++ni) {
                const int bb = brow0 + ni * 2048 + colswz[kk];
                bh[ni] = *(const s16x8*)((const char*)sBh + bb);
                bl[ni] = *(const s16x8*)((const char*)sBl + bb);
            }
#pragma unroll
            for (int mi = 0; mi < 4; ++mi)
#pragma unroll
                for (int ni = 0; ni < 2; ++ni)
                    acc[mi][ni] = __builtin_amdgcn_mfma_f32_16x16x32_bf16(
                        ah[mi], bh[ni], acc[mi][ni], 0, 0, 0);
#pragma unroll
            for (int mi = 0; mi < 4; ++mi)
#pragma unroll
                for (int ni = 0; ni < 2; ++ni)
                    acc[mi][ni] = __builtin_amdgcn_mfma_f32_16x16x32_bf16(
                        ah[mi], bl[ni], acc[mi][ni], 0, 0, 0);
#pragma unroll
            for (int mi = 0; mi < 4; ++mi)
#pragma unroll
                for (int ni = 0; ni < 2; ++ni)
                    acc[mi][ni] = __builtin_amdgcn_mfma_f32_16x16x32_bf16(
                        al[mi], bh[ni], acc[mi][ni], 0, 0, 0);
        }
        __syncthreads();
    }

    // epilogue: + sum_k g[b,k]*b_enc[k,h]; C/D: col=l&15, row=(l>>4)*4+j
    float bce[2][4];
#pragma unroll
    for (int ni = 0; ni < 2; ++ni) {
        const int col = colb + wc * 32 + ni * 16 + l15;
#pragma unroll
        for (int kk = 0; kk < 4; ++kk)
            bce[ni][kk] = benc[kk * NH + col];
    }
#pragma unroll
    for (int mi = 0; mi < 4; ++mi) {
#pragma unroll
        for (int j = 0; j < 4; ++j) {
            const int row = rowb + wr * 64 + mi * 16 + ls * 4 + j;
            const float4 g = *(const float4*)(gates + row * 4);
#pragma unroll
            for (int ni = 0; ni < 2; ++ni) {
                const int col = colb + wc * 32 + ni * 16 + l15;
                float bias = g.x * bce[ni][0] + g.y * bce[ni][1] +
                             g.z * bce[ni][2] + g.w * bce[ni][3];
                out[(size_t)row * NH + col] = acc[mi][ni][j] + bias;
            }
        }
    }
}

// ---------------------------------------------------------------------------
extern "C" void kernel_launch(void* const* d_in, const int* in_sizes, int n_in,
                              void* d_out, int out_size, void* d_ws, size_t ws_size,
                              hipStream_t stream)
{
    const float* ctx   = (const float*)d_in[0];
    const float* x     = (const float*)d_in[1];
    const float* gum   = (const float*)d_in[2];
    const float* W1    = (const float*)d_in[3];
    const float* b1    = (const float*)d_in[4];
    const float* gln   = (const float*)d_in[5];
    const float* bln   = (const float*)d_in[6];
    const float* W2    = (const float*)d_in[7];
    const float* b2    = (const float*)d_in[8];
    const float* W3    = (const float*)d_in[9];
    const float* b3    = (const float*)d_in[10];
    const float* prior = (const float*)d_in[11];
    const float* Wenc  = (const float*)d_in[12];
    const float* benc  = (const float*)d_in[13];
    const float* fw    = (const float*)d_in[14];
    float* out = (float*)d_out;

    // ws layout: gates 64KB | Bh 8MB | Bl 8MB | Ah 32MB | Al 32MB  (~80.1MB)
    char* ws = (char*)d_ws;
    float* gates        = (float*)ws;
    unsigned short* bh  = (unsigned short*)(ws + (64 << 10));
    unsigned short* bl  = (unsigned short*)(ws + (64 << 10) + (8ull << 20));
    unsigned short* ah  = (unsigned short*)(ws + (64 << 10) + (16ull << 20));
    unsigned short* al  = (unsigned short*)(ws + (64 << 10) + (48ull << 20));

    hipLaunchKernelGGL(router_k, dim3(256), dim3(256), 0, stream,
                       ctx, gum, W1, b1, gln, bln, W2, b2, W3, b3, prior, fw, gates);
    hipLaunchKernelGGL(aprep_k, dim3(8192), dim3(256), 0, stream, x, gates, ah, al);
    hipLaunchKernelGGL(wprep_k, dim3(4096), dim3(256), 0, stream, Wenc, bh, bl);
    hipLaunchKernelGGL(gemm_k, dim3(512), dim3(256), 0, stream,
                       ah, al, bh, bl, gates, benc, out);
}

// Round 3
// 225.270 us; speedup vs baseline: 2.3300x; 1.1758x over previous
//
#include <hip/hip_runtime.h>
#include <hip/hip_bf16.h>

#define NB    4096   // batch rows
#define NK    4      // modalities
#define ND    1024   // d_in
#define NH    1024   // hidden out
#define NCTX  256
#define NRH   64

typedef float f32x4 __attribute__((ext_vector_type(4)));
typedef float f32x8 __attribute__((ext_vector_type(8)));
typedef short s16x8 __attribute__((ext_vector_type(8)));
typedef _Float16 f16x8 __attribute__((ext_vector_type(8)));

#define RES_SCALE 2048.0f      // 2^11: keeps B-residual in f16 normal range
#define RES_INV   (1.0f/2048.0f)

__device__ __forceinline__ void gl_lds16(const void* g, void* l) {
    __builtin_amdgcn_global_load_lds(
        (const __attribute__((address_space(1))) unsigned int*)g,
        (__attribute__((address_space(3))) unsigned int*)l, 16, 0, 0);
}

// ---------------------------------------------------------------------------
// Kernel 1: router MLP -> gates[B][K] = (mask>0.5)*mask*softmax(fusion_w)[k]
// ---------------------------------------------------------------------------
__global__ __launch_bounds__(256) void router_k(
    const float* __restrict__ ctx, const float* __restrict__ gum,
    const float* __restrict__ W1, const float* __restrict__ b1,
    const float* __restrict__ gln, const float* __restrict__ bln,
    const float* __restrict__ W2, const float* __restrict__ b2,
    const float* __restrict__ W3, const float* __restrict__ b3,
    const float* __restrict__ prior, const float* __restrict__ fw,
    float* __restrict__ gates)
{
    __shared__ float sH[4][4][64];
    __shared__ float sH2[4][4][32];

    const int tid  = threadIdx.x;
    const int w    = tid >> 6;
    const int lane = tid & 63;
    const int rowbase = blockIdx.x * 16 + w * 4;
    const int rbu = __builtin_amdgcn_readfirstlane(rowbase);
    const float* c0 = ctx + (size_t)rbu * NCTX;

    float a0 = 0.f, a1 = 0.f, a2 = 0.f, a3 = 0.f;
#pragma unroll 8
    for (int d = 0; d < NCTX; ++d) {
        float wv = W1[d * NRH + lane];
        a0 = fmaf(c0[d],          wv, a0);
        a1 = fmaf(c0[NCTX + d],   wv, a1);
        a2 = fmaf(c0[2*NCTX + d], wv, a2);
        a3 = fmaf(c0[3*NCTX + d], wv, a3);
    }
    const float bb = b1[lane];
    float hr[4] = {a0 + bb, a1 + bb, a2 + bb, a3 + bb};
    const float gl = gln[lane], be = bln[lane];

#pragma unroll
    for (int r = 0; r < 4; ++r) {
        float h = hr[r];
        float s = h;
#pragma unroll
        for (int m = 32; m >= 1; m >>= 1) s += __shfl_xor(s, m);
        float mu = s * (1.f / 64.f);
        float dd = h - mu;
        float q = dd * dd;
#pragma unroll
        for (int m = 32; m >= 1; m >>= 1) q += __shfl_xor(q, m);
        float var = q * (1.f / 64.f);
        h = dd * rsqrtf(var + 1e-5f) * gl + be;
        sH[w][r][lane] = fmaxf(h, 0.f);
    }

#pragma unroll
    for (int p = 0; p < 2; ++p) {
        const int r = p * 2 + (lane >> 5);
        const int j = lane & 31;
        float acc = b2[j];
#pragma unroll 8
        for (int l = 0; l < 64; ++l)
            acc = fmaf(sH[w][r][l], W2[l * 32 + j], acc);
        sH2[w][r][j] = fmaxf(acc, 0.f);
    }

    const int r3 = lane >> 2, j3 = lane & 3;
    float lg = 0.f;
    if (lane < 16) {
        lg = b3[j3] + prior[j3];
#pragma unroll 8
        for (int l = 0; l < 32; ++l)
            lg = fmaf(sH2[w][r3][l], W3[l * 4 + j3], lg);
    }
    float pj = 1.f / (1.f + expf(-lg));
    const int base = lane & 60;
    float P0 = __shfl(pj, base), P1 = __shfl(pj, base | 1);
    float P2 = __shfl(pj, base | 2), P3 = __shfl(pj, base | 3);

    if (lane < 16) {
        float f0 = fw[0], f1 = fw[1], f2 = fw[2], f3 = fw[3];
        float fm = fmaxf(fmaxf(f0, f1), fmaxf(f2, f3));
        float e0 = expf(f0 - fm), e1 = expf(f1 - fm), e2 = expf(f2 - fm), e3 = expf(f3 - fm);
        float es = e0 + e1 + e2 + e3;
        float wsm = (j3 == 0 ? e0 : j3 == 1 ? e1 : j3 == 2 ? e2 : e3) / es;

        int cnt = 0;
        cnt += (P0 > pj) || ((P0 == pj) && (0 < j3));
        cnt += (P1 > pj) || ((P1 == pj) && (1 < j3));
        cnt += (P2 > pj) || ((P2 == pj) && (2 < j3));
        cnt += (P3 > pj) || ((P3 == pj) && (3 < j3));

        const int row = rowbase + r3;
        float soft = 1.f / (1.f + expf(-(lg + gum[row * 4 + j3])));
        float mask = (cnt < 2) ? 1.0f : soft;
        float gate = (mask > 0.5f) ? mask * wsm : 0.0f;
        gates[row * 4 + j3] = gate;
    }
}

// ---------------------------------------------------------------------------
// Kernel 2: W_enc [K][D][H] fp32 -> Bh f16 [K][H][D] + Bls f16 (residual*2^11)
// ---------------------------------------------------------------------------
__global__ __launch_bounds__(256) void wprep_k(
    const float* __restrict__ W, unsigned short* __restrict__ whi,
    unsigned short* __restrict__ wlo)
{
    __shared__ float sT[32][33];
    const int bid = blockIdx.x;
    const int k  = bid >> 10;
    const int dt = (bid >> 5) & 31;
    const int ht = bid & 31;
    const int t = threadIdx.x;
    {
        const int r  = t >> 3;
        const int c4 = (t & 7) << 2;
        const float* src = W + ((size_t)k << 20) + (size_t)(dt * 32 + r) * 1024 + (ht * 32 + c4);
        float4 v = *(const float4*)src;
        sT[c4 + 0][r] = v.x; sT[c4 + 1][r] = v.y;
        sT[c4 + 2][r] = v.z; sT[c4 + 3][r] = v.w;
    }
    __syncthreads();
    {
        const int h  = t >> 3;
        const int d4 = (t & 7) << 2;
        unsigned short uh[4], ul[4];
#pragma unroll
        for (int q = 0; q < 4; ++q) {
            float u = sT[h][d4 + q];
            _Float16 hi = (_Float16)u;
            _Float16 lo = (_Float16)((u - (float)hi) * RES_SCALE);
            uh[q] = __builtin_bit_cast(unsigned short, hi);
            ul[q] = __builtin_bit_cast(unsigned short, lo);
        }
        size_t o = ((size_t)k << 20) + (size_t)(ht * 32 + h) * 1024 + (dt * 32 + d4);
        *(ushort4*)(whi + o) = make_ushort4(uh[0], uh[1], uh[2], uh[3]);
        *(ushort4*)(wlo + o) = make_ushort4(ul[0], ul[1], ul[2], ul[3]);
    }
}

// ---------------------------------------------------------------------------
// Kernel 3: A-prep: Ah[b][ks*1024+d] = f16(x[ks,b,d] * gates[b,ks])
// ---------------------------------------------------------------------------
__global__ __launch_bounds__(256) void aprep_k(
    const float* __restrict__ x, const float* __restrict__ gates,
    unsigned short* __restrict__ Ah)
{
    const int bid = blockIdx.x;
    const int k  = bid >> 11;          // 0..3
    const int bp = bid & 2047;         // b pair
    const int t = threadIdx.x;
    const int boff = t >> 7;
    const int d8 = (t & 127) << 3;
    const int b = bp * 2 + boff;
    const float g = gates[b * 4 + k];

    f32x8 v = *(const f32x8*)(x + ((size_t)k << 22) + (size_t)b * ND + d8);
    v *= g;
    f16x8 hb = __builtin_convertvector(v, f16x8);
    const size_t o = (size_t)b * 4096 + (k << 10) + d8;
    *(s16x8*)(Ah + o) = __builtin_bit_cast(s16x8, hb);
}

// ---------------------------------------------------------------------------
// Kernel 4: f16 hi/lo 2-pass MFMA GEMM, double-buffered LDS, T3-min 2-phase.
// out = Ah·Bh + (Ah·Bls)·2^-11 + bias.  M=4096 N=1024 K=4096.
// BM=128 BN=64 BK=64; 4 waves 2x2 (wave tile 64x32); grid 512 (2 blk/CU).
// LDS 64KB (2 x {A 16KB + Bh 8KB + Bl 8KB}), T2 XOR-swizzle via
// pre-swizzled global src (rule 21).  One barrier per K-tile.
// ---------------------------------------------------------------------------
__global__ __launch_bounds__(256, 2) void gemm_k(
    const unsigned short* __restrict__ Ahg,
    const unsigned short* __restrict__ Bhg, const unsigned short* __restrict__ Blg,
    const float* __restrict__ gates, const float* __restrict__ benc,
    float* __restrict__ out)
{
    __shared__ unsigned short sA0[128 * 64], sA1[128 * 64];
    __shared__ unsigned short sBh0[64 * 64], sBh1[64 * 64];
    __shared__ unsigned short sBl0[64 * 64], sBl1[64 * 64];

    const int bid = blockIdx.x;
    const int wg  = (bid & 7) * 64 + (bid >> 3);   // XCD-grouped, bijective
    const int bm  = wg >> 4;               // 0..31
    const int bn  = wg & 15;               // 0..15

    const int tid = threadIdx.x;
    const int wv  = tid >> 6, ln = tid & 63;
    const int wr  = wv >> 1,  wc = wv & 1;
    const int l15 = ln & 15,  ls = ln >> 4;
    const int rowb = bm * 128;
    const int colb = bn * 64;

    // staging: LDS byte L = chunk*1024 + l*16 holds (row = L>>7,
    // col_bytes = (L&127) ^ ((row&7)<<4)); row = chunk*8 + (l>>3)
    const int srow = ln >> 3;
    const int slot = (ln & 7) ^ srow;
    size_t aoff[4];
#pragma unroll
    for (int i = 0; i < 4; ++i) {
        const int row = (wv * 4 + i) * 8 + srow;
        aoff[i] = (size_t)(rowb + row) * 4096 + slot * 8;
    }
    size_t boff[2];
#pragma unroll
    for (int i = 0; i < 2; ++i) {
        const int row = (wv * 2 + i) * 8 + srow;
        boff[i] = (size_t)(colb + row) * 1024 + slot * 8;
    }

    const int arow0 = (wr * 64 + l15) * 128;
    const int brow0 = (wc * 32 + l15) * 128;
    const int xr = (l15 & 7) << 4;
    int colswz[2];
#pragma unroll
    for (int kk = 0; kk < 2; ++kk)
        colswz[kk] = ((kk << 6) + (ls << 4)) ^ xr;

    f32x4 acch[4][2], accl[4][2];
#pragma unroll
    for (int a = 0; a < 4; ++a)
#pragma unroll
        for (int b = 0; b < 2; ++b) {
            acch[a][b] = (f32x4){0.f, 0.f, 0.f, 0.f};
            accl[a][b] = (f32x4){0.f, 0.f, 0.f, 0.f};
        }

#define STAGE(SA, SBH, SBL, KT)                                               \
    do {                                                                      \
        const int kb_ = (KT) * 64;                                            \
        const size_t wk_ = ((size_t)((KT) >> 4) << 20) + (size_t)((KT) & 15) * 64; \
        _Pragma("unroll")                                                     \
        for (int i = 0; i < 4; ++i)                                           \
            gl_lds16(Ahg + aoff[i] + kb_, &(SA)[(wv * 4 + i) * 512]);         \
        _Pragma("unroll")                                                     \
        for (int i = 0; i < 2; ++i) {                                         \
            gl_lds16(Bhg + boff[i] + wk_, &(SBH)[(wv * 2 + i) * 512]);        \
            gl_lds16(Blg + boff[i] + wk_, &(SBL)[(wv * 2 + i) * 512]);        \
        }                                                                     \
    } while (0)

#define COMPUTE(SA, SBH, SBL)                                                 \
    do {                                                                      \
        _Pragma("unroll")                                                     \
        for (int kk = 0; kk < 2; ++kk) {                                      \
            f16x8 ah[4], bh[2], bl[2];                                        \
            _Pragma("unroll")                                                 \
            for (int mi = 0; mi < 4; ++mi)                                    \
                ah[mi] = __builtin_bit_cast(f16x8, *(const s16x8*)((const char*)(SA) + arow0 + mi * 2048 + colswz[kk])); \
            _Pragma("unroll")                                                 \
            for (int ni = 0; ni < 2; ++ni) {                                  \
                bh[ni] = __builtin_bit_cast(f16x8, *(const s16x8*)((const char*)(SBH) + brow0 + ni * 2048 + colswz[kk])); \
                bl[ni] = __builtin_bit_cast(f16x8, *(const s16x8*)((const char*)(SBL) + brow0 + ni * 2048 + colswz[kk])); \
            }                                                                 \
            _Pragma("unroll")                                                 \
            for (int mi = 0; mi < 4; ++mi)                                    \
                _Pragma("unroll")                                             \
                for (int ni = 0; ni < 2; ++ni)                                \
                    acch[mi][ni] = __builtin_amdgcn_mfma_f32_16x16x32_f16(    \
                        ah[mi], bh[ni], acch[mi][ni], 0, 0, 0);               \
            _Pragma("unroll")                                                 \
            for (int mi = 0; mi < 4; ++mi)                                    \
                _Pragma("unroll")                                             \
                for (int ni = 0; ni < 2; ++ni)                                \
                    accl[mi][ni] = __builtin_amdgcn_mfma_f32_16x16x32_f16(    \
                        ah[mi], bl[ni], accl[mi][ni], 0, 0, 0);               \
        }                                                                     \
    } while (0)

    // ---- T3-minimum 2-phase: prologue stage, then {stage(next); compute(cur); bar}
    STAGE(sA0, sBh0, sBl0, 0);
    __syncthreads();                       // vmcnt(0) drain + barrier

#pragma unroll 1
    for (int kt = 0; kt < 64; kt += 2) {
        STAGE(sA1, sBh1, sBl1, kt + 1);    // issue next-tile loads (odd buf)
        COMPUTE(sA0, sBh0, sBl0);          // compute current (even buf)
        __syncthreads();                   // odd buf staged + even buf free
        if (kt + 2 < 64)
            STAGE(sA0, sBh0, sBl0, kt + 2);
        COMPUTE(sA1, sBh1, sBl1);
        __syncthreads();
    }
#undef STAGE
#undef COMPUTE

    // epilogue: out = acch + accl*2^-11 + sum_k g[b,k]*b_enc[k,h]
    // C/D frag: col=l&15, row=(l>>4)*4+j
    float bce[2][4];
#pragma unroll
    for (int ni = 0; ni < 2; ++ni) {
        const int col = colb + wc * 32 + ni * 16 + l15;
#pragma unroll
        for (int kk = 0; kk < 4; ++kk)
            bce[ni][kk] = benc[kk * NH + col];
    }
#pragma unroll
    for (int mi = 0; mi < 4; ++mi) {
#pragma unroll
        for (int j = 0; j < 4; ++j) {
            const int row = rowb + wr * 64 + mi * 16 + ls * 4 + j;
            const float4 g = *(const float4*)(gates + row * 4);
#pragma unroll
            for (int ni = 0; ni < 2; ++ni) {
                const int col = colb + wc * 32 + ni * 16 + l15;
                float bias = g.x * bce[ni][0] + g.y * bce[ni][1] +
                             g.z * bce[ni][2] + g.w * bce[ni][3];
                out[(size_t)row * NH + col] =
                    acch[mi][ni][j] + accl[mi][ni][j] * RES_INV + bias;
            }
        }
    }
}

// ---------------------------------------------------------------------------
extern "C" void kernel_launch(void* const* d_in, const int* in_sizes, int n_in,
                              void* d_out, int out_size, void* d_ws, size_t ws_size,
                              hipStream_t stream)
{
    const float* ctx   = (const float*)d_in[0];
    const float* x     = (const float*)d_in[1];
    const float* gum   = (const float*)d_in[2];
    const float* W1    = (const float*)d_in[3];
    const float* b1    = (const float*)d_in[4];
    const float* gln   = (const float*)d_in[5];
    const float* bln   = (const float*)d_in[6];
    const float* W2    = (const float*)d_in[7];
    const float* b2    = (const float*)d_in[8];
    const float* W3    = (const float*)d_in[9];
    const float* b3    = (const float*)d_in[10];
    const float* prior = (const float*)d_in[11];
    const float* Wenc  = (const float*)d_in[12];
    const float* benc  = (const float*)d_in[13];
    const float* fw    = (const float*)d_in[14];
    float* out = (float*)d_out;

    // ws layout: gates 64KB | Bh 8MB | Bls 8MB | Ah 32MB  (~48.1MB)
    char* ws = (char*)d_ws;
    float* gates        = (float*)ws;
    unsigned short* bh  = (unsigned short*)(ws + (64 << 10));
    unsigned short* bl  = (unsigned short*)(ws + (64 << 10) + (8ull << 20));
    unsigned short* ah  = (unsigned short*)(ws + (64 << 10) + (16ull << 20));

    hipLaunchKernelGGL(router_k, dim3(256), dim3(256), 0, stream,
                       ctx, gum, W1, b1, gln, bln, W2, b2, W3, b3, prior, fw, gates);
    hipLaunchKernelGGL(aprep_k, dim3(8192), dim3(256), 0, stream, x, gates, ah);
    hipLaunchKernelGGL(wprep_k, dim3(4096), dim3(256), 0, stream, Wenc, bh, bl);
    hipLaunchKernelGGL(gemm_k, dim3(512), dim3(256), 0, stream,
                       ah, bh, bl, gates, benc, out);
}